// Round 1
// baseline (442748.047 us; speedup 1.0000x reference)
//
#include <hip/hip_runtime.h>

#define T_STEPS 8192
#define HID 1024
#define G4 4096

typedef unsigned long long ull;

struct __align__(32) Slot { ull d[2]; int flag; int pad0; ull pad1; };

__device__ inline float sigm(float x) { return 1.0f / (1.0f + __expf(-x)); }
__device__ inline float tanh_f(float x) {
    x = fminf(fmaxf(x, -15.f), 15.f);
    float e = __expf(-2.0f * x);
    return (1.0f - e) / (1.0f + e);
}

// out[m][perm(n)] = A[m][:] . W[n][:] + bi[n] + bh[n]
// perm groups the 16 gate-rows each recurrence WG needs into one contiguous 64B slot:
// j = n&1023 (h index), gate = n>>10; idx = (j>>2)*16 + (j&3)*4 + gate
__global__ __launch_bounds__(256)
void gemm_xg(const float* __restrict__ A, const float* __restrict__ W,
             const float* __restrict__ bi, const float* __restrict__ bh,
             float* __restrict__ out)
{
    __shared__ float As[16][65];
    __shared__ float Bs[16][65];
    const int tid = threadIdx.x;
    const int m0 = blockIdx.y * 64, n0 = blockIdx.x * 64;
    const int tm = tid & 15, tn = tid >> 4;
    const int row = tid >> 2, q = tid & 3;
    float acc[4][4] = {{0.f}};
    for (int k0 = 0; k0 < HID; k0 += 16) {
        float4 a = *(const float4*)(A + (size_t)(m0 + row) * HID + k0 + q * 4);
        float4 b = *(const float4*)(W + (size_t)(n0 + row) * HID + k0 + q * 4);
        __syncthreads();
        As[q*4+0][row] = a.x; As[q*4+1][row] = a.y; As[q*4+2][row] = a.z; As[q*4+3][row] = a.w;
        Bs[q*4+0][row] = b.x; Bs[q*4+1][row] = b.y; Bs[q*4+2][row] = b.z; Bs[q*4+3][row] = b.w;
        __syncthreads();
#pragma unroll
        for (int kk = 0; kk < 16; ++kk) {
            float av[4], bv[4];
#pragma unroll
            for (int i = 0; i < 4; ++i) { av[i] = As[kk][tm*4+i]; bv[i] = Bs[kk][tn*4+i]; }
#pragma unroll
            for (int i = 0; i < 4; ++i)
#pragma unroll
                for (int j = 0; j < 4; ++j) acc[i][j] += av[i] * bv[j];
        }
    }
#pragma unroll
    for (int i = 0; i < 4; ++i) {
        int m = m0 + tm * 4 + i;
#pragma unroll
        for (int j = 0; j < 4; ++j) {
            int n = n0 + tn * 4 + j;
            float v = acc[i][j] + bi[n] + bh[n];
            int jd = n & (HID - 1), gate = n >> 10;
            out[(size_t)m * G4 + (jd >> 2) * 16 + (jd & 3) * 4 + gate] = v;
        }
    }
}

// Persistent recurrence: 256 WGs, each owns h indices [4k, 4k+4).
// Wave w of WG k owns h index j=4k+w and all 4 gates for it (rows jj*4+gate in LDS).
// Per step: compute 4 dots from LDS-resident W slice + LDS h, gate math on lane 0,
// publish 16B h-chunk + release flag to global slots, poll all 256 slots, rebuild h in LDS.
// Double-buffered slots (parity t&1); flag==t means "h after step t". Poison 0xAA = negative.
__global__ __launch_bounds__(256)
void lstm_recur(const float* __restrict__ Whh, const float* __restrict__ xg,
                float* __restrict__ yhist, float* __restrict__ outF,
                Slot* __restrict__ slots)
{
    __shared__ float Wl[16 * HID];   // 64 KB: rows [jj*4+gate][1024]
    __shared__ float hl[HID];
    __shared__ float hout[4];
    const int k = blockIdx.x, tid = threadIdx.x;
    const int wave = tid >> 6, lane = tid & 63;

    // Stage W_hh slice: LDS row r=jj*4+gate  <-  global row gate*1024 + (4k+jj)
#pragma unroll
    for (int r = 0; r < 16; ++r) {
        int jj = r >> 2, g = r & 3;
        const float4* src = (const float4*)(Whh + (size_t)(g * HID + k * 4 + jj) * HID);
        ((float4*)(Wl + r * HID))[tid] = src[tid];
    }
    for (int i = tid; i < HID; i += 256) hl[i] = 0.f;
    float c_state = 0.f;   // live on lane 0 of each wave
    __syncthreads();

    for (int t = 0; t < T_STEPS; ++t) {
        float4 xgv = make_float4(0.f, 0.f, 0.f, 0.f);
        if (lane == 0)
            xgv = ((const float4*)(xg + (size_t)t * G4 + k * 16))[wave];

        float a0 = 0.f, a1 = 0.f, a2 = 0.f, a3 = 0.f;
        const float* wb = Wl + wave * 4 * HID;
#pragma unroll 4
        for (int u = 0; u < 16; ++u) {
            float hv = hl[u * 64 + lane];
            a0 += wb[0 * HID + u * 64 + lane] * hv;
            a1 += wb[1 * HID + u * 64 + lane] * hv;
            a2 += wb[2 * HID + u * 64 + lane] * hv;
            a3 += wb[3 * HID + u * 64 + lane] * hv;
        }
#pragma unroll
        for (int off = 32; off > 0; off >>= 1) {
            a0 += __shfl_xor(a0, off, 64);
            a1 += __shfl_xor(a1, off, 64);
            a2 += __shfl_xor(a2, off, 64);
            a3 += __shfl_xor(a3, off, 64);
        }
        if (lane == 0) {
            float ig = sigm(xgv.x + a0);
            float fg = sigm(xgv.y + a1);
            float gg = tanh_f(xgv.z + a2);
            float og = sigm(xgv.w + a3);
            c_state = fg * c_state + ig * gg;
            hout[wave] = og * tanh_f(c_state);
        }
        __syncthreads();   // hout ready; everyone done reading hl

        if (tid == 0) {
            union { float4 v; ull u[2]; } cv;
            cv.v = *(float4*)hout;
            Slot* sl = slots + (t & 1) * 256 + k;
            __hip_atomic_store(&sl->d[0], cv.u[0], __ATOMIC_RELAXED, __HIP_MEMORY_SCOPE_AGENT);
            __hip_atomic_store(&sl->d[1], cv.u[1], __ATOMIC_RELAXED, __HIP_MEMORY_SCOPE_AGENT);
            __hip_atomic_store(&sl->flag, t, __ATOMIC_RELEASE, __HIP_MEMORY_SCOPE_AGENT);
            if (yhist) *(float4*)(yhist + (size_t)t * HID + 4 * k) = cv.v;
            if (outF && t == T_STEPS - 1) *(float4*)(outF + 4 * k) = cv.v;
        }
        // Gather h_t: thread i polls slot i, writes hl[4i..4i+4)
        {
            Slot* s2 = slots + (t & 1) * 256 + tid;
            while (__hip_atomic_load(&s2->flag, __ATOMIC_ACQUIRE, __HIP_MEMORY_SCOPE_AGENT) < t)
                __builtin_amdgcn_s_sleep(1);
            union { float4 v; ull u[2]; } cv;
            cv.u[0] = __hip_atomic_load(&s2->d[0], __ATOMIC_RELAXED, __HIP_MEMORY_SCOPE_AGENT);
            cv.u[1] = __hip_atomic_load(&s2->d[1], __ATOMIC_RELAXED, __HIP_MEMORY_SCOPE_AGENT);
            *(float4*)(hl + 4 * tid) = cv.v;
        }
        __syncthreads();   // hl = h_t ready for next iteration
    }
}

extern "C" void kernel_launch(void* const* d_in, const int* in_sizes, int n_in,
                              void* d_out, int out_size, void* d_ws, size_t ws_size,
                              hipStream_t stream)
{
    const float* x    = (const float*)d_in[0];
    const float* Wih0 = (const float*)d_in[1];
    const float* Whh0 = (const float*)d_in[2];
    const float* bih0 = (const float*)d_in[3];
    const float* bhh0 = (const float*)d_in[4];
    const float* Wih1 = (const float*)d_in[5];
    const float* Whh1 = (const float*)d_in[6];
    const float* bih1 = (const float*)d_in[7];
    const float* bhh1 = (const float*)d_in[8];

    char* ws = (char*)d_ws;
    float* xg = (float*)ws;                            // 8192*4096*4 = 134217728 B (permuted gates)
    float* y0 = (float*)(ws + 134217728);              // 8192*1024*4 = 33554432 B
    Slot*  s0 = (Slot*)(ws + 167772160);               // 2*256*32 = 16384 B
    Slot*  s1 = (Slot*)(ws + 167788544);               // 16384 B

    dim3 gg(G4 / 64, T_STEPS / 64);
    gemm_xg<<<gg, 256, 0, stream>>>(x, Wih0, bih0, bhh0, xg);
    lstm_recur<<<256, 256, 0, stream>>>(Whh0, xg, y0, nullptr, s0);
    gemm_xg<<<gg, 256, 0, stream>>>(y0, Wih1, bih1, bhh1, xg);
    lstm_recur<<<256, 256, 0, stream>>>(Whh1, xg, nullptr, (float*)d_out, s1);
}

// Round 3
// 402116.333 us; speedup vs baseline: 1.1010x; 1.1010x over previous
//
#include <hip/hip_runtime.h>

#define T_STEPS 8192
#define HID 1024
#define G4 4096

typedef unsigned long long ull;

// Communication block, zeroed each launch via hipMemsetAsync:
//   hdata[p][512]  : packed h vector (as ull pairs) for parity p
//   cnt[p][8][16]  : 8 monotonic group counters per parity, 64B-strided lines.
//                    Producer wave (block k, wave w) adds 1 to cnt[p][k>>5] after
//                    storing h[4k+w]; target for occurrence n is 128*(n+1).
struct Comm {
    ull hdata[2][HID / 2];
    int cnt[2][8][16];
};

__device__ inline float sigm(float x) { return 1.0f / (1.0f + __expf(-x)); }
__device__ inline float tanh_f(float x) {
    x = fminf(fmaxf(x, -15.f), 15.f);
    float e = __expf(-2.0f * x);
    return (1.0f - e) / (1.0f + e);
}

// out[m][perm(n)] = A[m][:] . W[n][:] + bi[n] + bh[n]
// perm groups the 16 gate-rows each recurrence WG needs into one contiguous 64B slot:
// j = n&1023 (h index), gate = n>>10; idx = (j>>2)*16 + (j&3)*4 + gate
__global__ __launch_bounds__(256)
void gemm_xg(const float* __restrict__ A, const float* __restrict__ W,
             const float* __restrict__ bi, const float* __restrict__ bh,
             float* __restrict__ out)
{
    __shared__ float As[16][65];
    __shared__ float Bs[16][65];
    const int tid = threadIdx.x;
    const int m0 = blockIdx.y * 64, n0 = blockIdx.x * 64;
    const int tm = tid & 15, tn = tid >> 4;
    const int row = tid >> 2, q = tid & 3;
    float acc[4][4] = {{0.f}};
    for (int k0 = 0; k0 < HID; k0 += 16) {
        float4 a = *(const float4*)(A + (size_t)(m0 + row) * HID + k0 + q * 4);
        float4 b = *(const float4*)(W + (size_t)(n0 + row) * HID + k0 + q * 4);
        __syncthreads();
        As[q*4+0][row] = a.x; As[q*4+1][row] = a.y; As[q*4+2][row] = a.z; As[q*4+3][row] = a.w;
        Bs[q*4+0][row] = b.x; Bs[q*4+1][row] = b.y; Bs[q*4+2][row] = b.z; Bs[q*4+3][row] = b.w;
        __syncthreads();
#pragma unroll
        for (int kk = 0; kk < 16; ++kk) {
            float av[4], bv[4];
#pragma unroll
            for (int i = 0; i < 4; ++i) { av[i] = As[kk][tm*4+i]; bv[i] = Bs[kk][tn*4+i]; }
#pragma unroll
            for (int i = 0; i < 4; ++i)
#pragma unroll
                for (int j = 0; j < 4; ++j) acc[i][j] += av[i] * bv[j];
        }
    }
#pragma unroll
    for (int i = 0; i < 4; ++i) {
        int m = m0 + tm * 4 + i;
#pragma unroll
        for (int j = 0; j < 4; ++j) {
            int n = n0 + tn * 4 + j;
            float v = acc[i][j] + bi[n] + bh[n];
            int jd = n & (HID - 1), gate = n >> 10;
            out[(size_t)m * G4 + (jd >> 2) * 16 + (jd & 3) * 4 + gate] = v;
        }
    }
}

// Persistent recurrence: 256 WGs, each owns h indices [4k, 4k+4).
// Wave w owns h index 4k+w and its 4 gate rows (LDS-resident W_hh slice, 64 KB).
// Per step: dot from LDS, wave shuffle-reduce, lane0 gate math, lane0 publishes
// h float + release-add on group counter. Only tid<8 poll (8 counters); then all
// threads one-shot-acquire + load the packed 4 KB h and rebuild LDS h.
__global__ __launch_bounds__(256)
void lstm_recur(const float* __restrict__ Whh, const float* __restrict__ xg,
                float* __restrict__ yhist, float* __restrict__ outF,
                Comm* __restrict__ cm)
{
    __shared__ float Wl[16 * HID];   // rows [jj*4+gate][1024]
    __shared__ float hl[HID];
    const int k = blockIdx.x, tid = threadIdx.x;
    const int wave = tid >> 6, lane = tid & 63;

    // Stage W_hh slice: LDS row r=jj*4+gate  <-  global row gate*1024 + (4k+jj)
#pragma unroll
    for (int r = 0; r < 16; ++r) {
        int jj = r >> 2, g = r & 3;
        const float4* src = (const float4*)(Whh + (size_t)(g * HID + k * 4 + jj) * HID);
        ((float4*)(Wl + r * HID))[tid] = src[tid];
    }
    for (int i = tid; i < HID; i += 256) hl[i] = 0.f;
    float c_state = 0.f;   // live on lane 0 of each wave
    __syncthreads();

    for (int t = 0; t < T_STEPS; ++t) {
        const int p = t & 1, n = t >> 1;

        float xg0 = 0.f, xg1 = 0.f, xg2 = 0.f, xg3 = 0.f;
        if (lane == 0) {
            const float* xp = xg + (size_t)t * G4 + k * 16 + wave * 4;
            xg0 = xp[0]; xg1 = xp[1]; xg2 = xp[2]; xg3 = xp[3];
        }

        float a0 = 0.f, a1 = 0.f, a2 = 0.f, a3 = 0.f;
        const float* wb = Wl + wave * 4 * HID;
#pragma unroll 4
        for (int u = 0; u < 16; ++u) {
            float hv = hl[u * 64 + lane];
            a0 += wb[0 * HID + u * 64 + lane] * hv;
            a1 += wb[1 * HID + u * 64 + lane] * hv;
            a2 += wb[2 * HID + u * 64 + lane] * hv;
            a3 += wb[3 * HID + u * 64 + lane] * hv;
        }
#pragma unroll
        for (int off = 32; off > 0; off >>= 1) {
            a0 += __shfl_xor(a0, off, 64);
            a1 += __shfl_xor(a1, off, 64);
            a2 += __shfl_xor(a2, off, 64);
            a3 += __shfl_xor(a3, off, 64);
        }

        if (lane == 0) {
            float ig = sigm(xg0 + a0);
            float fg = sigm(xg1 + a1);
            float gg = tanh_f(xg2 + a2);
            float og = sigm(xg3 + a3);
            c_state = fg * c_state + ig * gg;
            float h = og * tanh_f(c_state);
            union { float f; unsigned u; } hu; hu.f = h;
            if (t < T_STEPS - 1) {
                // publish: data store (relaxed, 4B view into ull array) then release add
                __hip_atomic_store((unsigned*)&cm->hdata[p][0] + (4 * k + wave), hu.u,
                                   __ATOMIC_RELAXED, __HIP_MEMORY_SCOPE_AGENT);
                __hip_atomic_fetch_add(&cm->cnt[p][k >> 5][0], 1,
                                       __ATOMIC_RELEASE, __HIP_MEMORY_SCOPE_AGENT);
            }
            if (yhist) yhist[(size_t)t * HID + 4 * k + wave] = h;
            if (outF && t == T_STEPS - 1) outF[4 * k + wave] = h;
        }
        if (t == T_STEPS - 1) break;

        // wait: only 8 pollers per block, one counter line each
        if (tid < 8) {
            const int target = 128 * (n + 1);
            while (__hip_atomic_load(&cm->cnt[p][tid][0],
                                     __ATOMIC_RELAXED, __HIP_MEMORY_SCOPE_AGENT) < target)
                __builtin_amdgcn_s_sleep(1);
        }
        __syncthreads();

        // one-shot acquire on this thread's group counter, then 16 B data load
        (void)__hip_atomic_load(&cm->cnt[p][tid >> 5][0],
                                __ATOMIC_ACQUIRE, __HIP_MEMORY_SCOPE_AGENT);
        ull d0 = __hip_atomic_load(&cm->hdata[p][2 * tid + 0],
                                   __ATOMIC_RELAXED, __HIP_MEMORY_SCOPE_AGENT);
        ull d1 = __hip_atomic_load(&cm->hdata[p][2 * tid + 1],
                                   __ATOMIC_RELAXED, __HIP_MEMORY_SCOPE_AGENT);
        union { ull u[2]; float f[4]; } cv; cv.u[0] = d0; cv.u[1] = d1;
        hl[4 * tid + 0] = cv.f[0];
        hl[4 * tid + 1] = cv.f[1];
        hl[4 * tid + 2] = cv.f[2];
        hl[4 * tid + 3] = cv.f[3];
        __syncthreads();
    }
}

extern "C" void kernel_launch(void* const* d_in, const int* in_sizes, int n_in,
                              void* d_out, int out_size, void* d_ws, size_t ws_size,
                              hipStream_t stream)
{
    const float* x    = (const float*)d_in[0];
    const float* Wih0 = (const float*)d_in[1];
    const float* Whh0 = (const float*)d_in[2];
    const float* bih0 = (const float*)d_in[3];
    const float* bhh0 = (const float*)d_in[4];
    const float* Wih1 = (const float*)d_in[5];
    const float* Whh1 = (const float*)d_in[6];
    const float* bih1 = (const float*)d_in[7];
    const float* bhh1 = (const float*)d_in[8];

    char* ws = (char*)d_ws;
    float* xg = (float*)ws;                     // 8192*4096*4 = 134217728 B (permuted gates)
    float* y0 = (float*)(ws + 134217728);       // 8192*1024*4 = 33554432 B
    Comm*  c0 = (Comm*)(ws + 167772160);        // 5120 B, pad to 16 KB
    Comm*  c1 = (Comm*)(ws + 167772160 + 16384);

    // zero both comm blocks (counters monotonic within a dispatch; re-poisoned each launch)
    (void)hipMemsetAsync(ws + 167772160, 0, 32768, stream);

    dim3 gg(G4 / 64, T_STEPS / 64);
    gemm_xg<<<gg, 256, 0, stream>>>(x, Wih0, bih0, bhh0, xg);
    lstm_recur<<<256, 256, 0, stream>>>(Whh0, xg, y0, nullptr, c0);
    gemm_xg<<<gg, 256, 0, stream>>>(y0, Wih1, bih1, bhh1, xg);
    lstm_recur<<<256, 256, 0, stream>>>(Whh1, xg, nullptr, (float*)d_out, c1);
}

// Round 4
// 125424.890 us; speedup vs baseline: 3.5300x; 3.2060x over previous
//
#include <hip/hip_runtime.h>

#define T_STEPS 8192
#define HID 1024
#define G4 4096
#define NBLK 128   // recurrence blocks; each owns 8 h-indices
#define NTHR 512   // 8 waves

typedef unsigned long long ull;

// Comm block (zeroed each launch):
//   hdata[p][512] : packed h (ull pairs) for parity p
//   flags_u[64]   : 128 int flags viewed as 64 ull for vector polling.
//                   flags[k] == t+1  means block k published h_t into hdata[t&1].
struct Comm {
    ull hdata[2][HID / 2];
    ull flags_u[NBLK / 2];
};

__device__ inline float sigm(float x) { return 1.0f / (1.0f + __expf(-x)); }
__device__ inline float tanh_f(float x) {
    x = fminf(fmaxf(x, -15.f), 15.f);
    float e = __expf(-2.0f * x);
    return (1.0f - e) / (1.0f + e);
}

// out[m][perm(n)] = A[m][:] . W[n][:] + bi[n] + bh[n]
// perm groups the 32 gate-values each recurrence block reads per step contiguously:
// j = n&1023, gate = n>>10; idx = (j>>3)*32 + (j&7)*4 + gate
__global__ __launch_bounds__(256)
void gemm_xg(const float* __restrict__ A, const float* __restrict__ W,
             const float* __restrict__ bi, const float* __restrict__ bh,
             float* __restrict__ out)
{
    __shared__ float As[16][65];
    __shared__ float Bs[16][65];
    const int tid = threadIdx.x;
    const int m0 = blockIdx.y * 64, n0 = blockIdx.x * 64;
    const int tm = tid & 15, tn = tid >> 4;
    const int row = tid >> 2, q = tid & 3;
    float acc[4][4] = {{0.f}};
    for (int k0 = 0; k0 < HID; k0 += 16) {
        float4 a = *(const float4*)(A + (size_t)(m0 + row) * HID + k0 + q * 4);
        float4 b = *(const float4*)(W + (size_t)(n0 + row) * HID + k0 + q * 4);
        __syncthreads();
        As[q*4+0][row] = a.x; As[q*4+1][row] = a.y; As[q*4+2][row] = a.z; As[q*4+3][row] = a.w;
        Bs[q*4+0][row] = b.x; Bs[q*4+1][row] = b.y; Bs[q*4+2][row] = b.z; Bs[q*4+3][row] = b.w;
        __syncthreads();
#pragma unroll
        for (int kk = 0; kk < 16; ++kk) {
            float av[4], bv[4];
#pragma unroll
            for (int i = 0; i < 4; ++i) { av[i] = As[kk][tm*4+i]; bv[i] = Bs[kk][tn*4+i]; }
#pragma unroll
            for (int i = 0; i < 4; ++i)
#pragma unroll
                for (int j = 0; j < 4; ++j) acc[i][j] += av[i] * bv[j];
        }
    }
#pragma unroll
    for (int i = 0; i < 4; ++i) {
        int m = m0 + tm * 4 + i;
#pragma unroll
        for (int j = 0; j < 4; ++j) {
            int n = n0 + tn * 4 + j;
            float v = acc[i][j] + bi[n] + bh[n];
            int jd = n & (HID - 1), gate = n >> 10;
            out[(size_t)m * G4 + (jd >> 3) * 32 + (jd & 7) * 4 + gate] = v;
        }
    }
}

// Persistent recurrence: 128 WGs x 512 thr. Block k owns h[8k..8k+8); wave w owns
// h index 8k+w and its 4 gate rows (fp32 W_hh slice resident in LDS, 131 KB).
// Per step: LDS dot + wave shuffle-reduce; lane0 gate math -> hpubf[w];
// wave0: lanes 0..3 pack+store 32B hdata (relaxed agent), lane... tid0 release
// flag (wave-shared vmcnt orders the data stores under it); wave0 polls ALL 128
// flags with one 64-lane ull relaxed load per round; then all 512 threads read
// the 4KB h vector (relaxed agent) and rebuild LDS h.  No RMW anywhere.
__global__ __launch_bounds__(NTHR)
void lstm_recur(const float* __restrict__ Whh, const float* __restrict__ xg,
                float* __restrict__ yhist, float* __restrict__ outF,
                Comm* __restrict__ cm)
{
    __shared__ float Wl[32 * HID];   // rows [w*4+gate][1024]
    __shared__ float hl[HID];
    __shared__ float hpubf[8];
    const int k = blockIdx.x, tid = threadIdx.x;
    const int wave = tid >> 6, lane = tid & 63;

    // Stage W_hh slice: LDS row r=w*4+g  <-  global row g*1024 + (8k+w)
#pragma unroll
    for (int i = 0; i < 16; ++i) {
        int l = i * NTHR + tid;          // 0..8191 float4s
        int r = l >> 8, c = l & 255;
        int w = r >> 2, g = r & 3;
        ((float4*)(Wl + r * HID))[c] =
            ((const float4*)(Whh + (size_t)(g * HID + 8 * k + w) * HID))[c];
    }
    for (int i = tid; i < HID; i += NTHR) hl[i] = 0.f;
    float c_state = 0.f;   // lane 0 of each wave
    __syncthreads();

    for (int t = 0; t < T_STEPS; ++t) {
        const int p = t & 1;

        float xg0 = 0.f, xg1 = 0.f, xg2 = 0.f, xg3 = 0.f;
        if (lane == 0) {
            const float* xp = xg + (size_t)t * G4 + k * 32 + wave * 4;
            xg0 = xp[0]; xg1 = xp[1]; xg2 = xp[2]; xg3 = xp[3];
        }

        float a0 = 0.f, a1 = 0.f, a2 = 0.f, a3 = 0.f;
        const float* wb = Wl + wave * 4 * HID;
#pragma unroll 4
        for (int u = 0; u < 16; ++u) {
            float hv = hl[u * 64 + lane];
            a0 += wb[0 * HID + u * 64 + lane] * hv;
            a1 += wb[1 * HID + u * 64 + lane] * hv;
            a2 += wb[2 * HID + u * 64 + lane] * hv;
            a3 += wb[3 * HID + u * 64 + lane] * hv;
        }
#pragma unroll
        for (int off = 32; off > 0; off >>= 1) {
            a0 += __shfl_xor(a0, off, 64);
            a1 += __shfl_xor(a1, off, 64);
            a2 += __shfl_xor(a2, off, 64);
            a3 += __shfl_xor(a3, off, 64);
        }

        if (lane == 0) {
            float ig = sigm(xg0 + a0);
            float fg = sigm(xg1 + a1);
            float gg = tanh_f(xg2 + a2);
            float og = sigm(xg3 + a3);
            c_state = fg * c_state + ig * gg;
            float h = og * tanh_f(c_state);
            hpubf[wave] = h;
            if (yhist) yhist[(size_t)t * HID + 8 * k + wave] = h;
            if (outF && t == T_STEPS - 1) outF[8 * k + wave] = h;
        }
        if (t == T_STEPS - 1) break;

        __syncthreads();   // hpubf ready; everyone done reading hl

        if (wave == 0) {
            // lanes 0..3: pack 2 floats -> 1 ull, relaxed agent store (32 B total)
            if (lane < 4) {
                union { float f[2]; ull u; } pk;
                pk.f[0] = hpubf[2 * lane]; pk.f[1] = hpubf[2 * lane + 1];
                __hip_atomic_store(&cm->hdata[p][(size_t)k * 4 + lane], pk.u,
                                   __ATOMIC_RELAXED, __HIP_MEMORY_SCOPE_AGENT);
            }
            // lane 0: release flag — its s_waitcnt vmcnt(0) covers lanes 0..3's
            // stores (vmcnt is per-wave), so data is agent-visible before flag.
            if (lane == 0)
                __hip_atomic_store((int*)cm->flags_u + k, t + 1,
                                   __ATOMIC_RELEASE, __HIP_MEMORY_SCOPE_AGENT);
            // poll: 64 lanes x 2 flags in ONE relaxed vector load per round
            const int tp = t + 1;
            for (;;) {
                ull f = __hip_atomic_load(&cm->flags_u[lane],
                                          __ATOMIC_RELAXED, __HIP_MEMORY_SCOPE_AGENT);
                if (__all(((int)f >= tp) && ((int)(f >> 32) >= tp))) break;
            }
        }
        __syncthreads();   // all flags >= t+1: every block's h_t is at the coherence point

        // each thread: 8 B relaxed agent load -> 2 floats of h_t
        {
            union { ull u; float f[2]; } cv;
            cv.u = __hip_atomic_load(&cm->hdata[p][tid],
                                     __ATOMIC_RELAXED, __HIP_MEMORY_SCOPE_AGENT);
            hl[2 * tid + 0] = cv.f[0];
            hl[2 * tid + 1] = cv.f[1];
        }
        __syncthreads();   // hl = h_t ready
    }
}

extern "C" void kernel_launch(void* const* d_in, const int* in_sizes, int n_in,
                              void* d_out, int out_size, void* d_ws, size_t ws_size,
                              hipStream_t stream)
{
    const float* x    = (const float*)d_in[0];
    const float* Wih0 = (const float*)d_in[1];
    const float* Whh0 = (const float*)d_in[2];
    const float* bih0 = (const float*)d_in[3];
    const float* bhh0 = (const float*)d_in[4];
    const float* Wih1 = (const float*)d_in[5];
    const float* Whh1 = (const float*)d_in[6];
    const float* bih1 = (const float*)d_in[7];
    const float* bhh1 = (const float*)d_in[8];

    char* ws = (char*)d_ws;
    float* xg = (float*)ws;                     // 8192*4096*4 = 134217728 B (permuted gates)
    float* y0 = (float*)(ws + 134217728);       // 8192*1024*4 = 33554432 B
    Comm*  c0 = (Comm*)(ws + 167772160);        // 8704 B, padded to 16 KB
    Comm*  c1 = (Comm*)(ws + 167772160 + 16384);

    // zero both comm blocks (flags monotonic within a dispatch)
    (void)hipMemsetAsync(ws + 167772160, 0, 32768, stream);

    dim3 gg(G4 / 64, T_STEPS / 64);
    gemm_xg<<<gg, 256, 0, stream>>>(x, Wih0, bih0, bhh0, xg);
    lstm_recur<<<NBLK, NTHR, 0, stream>>>(Whh0, xg, y0, nullptr, c0);
    gemm_xg<<<gg, 256, 0, stream>>>(y0, Wih1, bih1, bhh1, xg);
    lstm_recur<<<NBLK, NTHR, 0, stream>>>(Whh1, xg, nullptr, (float*)d_out, c1);
}

// Round 5
// 67779.218 us; speedup vs baseline: 6.5322x; 1.8505x over previous
//
#include <hip/hip_runtime.h>

#define T_STEPS 8192
#define HID 1024
#define G4 4096
#define NBLK 128    // blocks per layer; total grid = 256
#define NTHR 512    // 8 waves

typedef unsigned long long ull;

// Comm block (zeroed each launch via hipMemsetAsync):
//   hA[p][512] : layer-0 h (h0) parity buffers, packed as ull pairs
//   hB[p][512] : layer-1 h (h1) parity buffers
//   flags[128] : 256 int flags. ints 0..127 = A flags (block k -> t+1 after
//                publishing h0_t); ints 128..255 = B flags (t+1 after h1_t).
//                Wait condition at step t (both cohorts): A>=t+1 && B>=t.
struct Comm {
    ull hA[2][HID / 2];
    ull hB[2][HID / 2];
    ull flags[128];
};

__device__ inline float sigm(float x) { return 1.0f / (1.0f + __expf(-x)); }
__device__ inline float tanh_f(float x) {
    x = fminf(fmaxf(x, -15.f), 15.f);
    float e = __expf(-2.0f * x);
    return (1.0f - e) / (1.0f + e);
}

// out[m][perm(n)] = A[m][:] . W[n][:] + bi[n] + bh[n]
// perm: j = n&1023, gate = n>>10; idx = (j>>3)*32 + (j&7)*4 + gate
// so recurrence block k's 32 gate values per step are contiguous at k*32.
__global__ __launch_bounds__(256)
void gemm_xg(const float* __restrict__ A, const float* __restrict__ W,
             const float* __restrict__ bi, const float* __restrict__ bh,
             float* __restrict__ out)
{
    __shared__ float As[16][65];
    __shared__ float Bs[16][65];
    const int tid = threadIdx.x;
    const int m0 = blockIdx.y * 64, n0 = blockIdx.x * 64;
    const int tm = tid & 15, tn = tid >> 4;
    const int row = tid >> 2, q = tid & 3;
    float acc[4][4] = {{0.f}};
    for (int k0 = 0; k0 < HID; k0 += 16) {
        float4 a = *(const float4*)(A + (size_t)(m0 + row) * HID + k0 + q * 4);
        float4 b = *(const float4*)(W + (size_t)(n0 + row) * HID + k0 + q * 4);
        __syncthreads();
        As[q*4+0][row] = a.x; As[q*4+1][row] = a.y; As[q*4+2][row] = a.z; As[q*4+3][row] = a.w;
        Bs[q*4+0][row] = b.x; Bs[q*4+1][row] = b.y; Bs[q*4+2][row] = b.z; Bs[q*4+3][row] = b.w;
        __syncthreads();
#pragma unroll
        for (int kk = 0; kk < 16; ++kk) {
            float av[4], bv[4];
#pragma unroll
            for (int i = 0; i < 4; ++i) { av[i] = As[kk][tm*4+i]; bv[i] = Bs[kk][tn*4+i]; }
#pragma unroll
            for (int i = 0; i < 4; ++i)
#pragma unroll
                for (int j = 0; j < 4; ++j) acc[i][j] += av[i] * bv[j];
        }
    }
#pragma unroll
    for (int i = 0; i < 4; ++i) {
        int m = m0 + tm * 4 + i;
#pragma unroll
        for (int j = 0; j < 4; ++j) {
            int n = n0 + tn * 4 + j;
            float v = acc[i][j] + bi[n] + bh[n];
            int jd = n & (HID - 1), gate = n >> 10;
            out[(size_t)m * G4 + (jd >> 3) * 32 + (jd & 7) * 4 + gate] = v;
        }
    }
}

// Shared poll: wave0 lanes each check 4 flags (2 ull loads) per round.
// Lanes 0..31 cover A flags (need >= t+1), lanes 32..63 cover B (need >= t).
__device__ inline void poll_flags(Comm* cm, int t, int lane)
{
    const int thr = (lane < 32) ? (t + 1) : t;
    for (;;) {
        ull f0 = __hip_atomic_load(&cm->flags[2 * lane + 0],
                                   __ATOMIC_RELAXED, __HIP_MEMORY_SCOPE_AGENT);
        ull f1 = __hip_atomic_load(&cm->flags[2 * lane + 1],
                                   __ATOMIC_RELAXED, __HIP_MEMORY_SCOPE_AGENT);
        bool ok = ((int)f0 >= thr) & ((int)(f0 >> 32) >= thr) &
                  ((int)f1 >= thr) & ((int)(f1 >> 32) >= thr);
        if (__all(ok)) break;
    }
}

// Fused 2-layer persistent LSTM. Grid = 256 blocks x 512 thr, all co-resident.
// Blocks 0..127   (layer 0): h0 recurrence; xg0 precomputed by gemm_xg.
//   loop t: compute h0_t from LDS hlA (=h0_{t-1}) -> publish hA/flagA=t+1 ->
//           poll -> gather hlA = h0_t.
// Blocks 128..255 (layer 1): W_hh1 slice in LDS, W_ih1 slice in 64 VGPRs/thread.
//   loop t: poll(A>=t+1,B>=t) -> gather h0_t + h1_{t-1} -> compute h1_t
//           (gates = Wih1.h0_t + Whh1.h1_{t-1} + biases) -> publish hB/flagB.
//   At t=T-1 write d_out instead of publishing.
__global__ __launch_bounds__(NTHR, 2)
void lstm_fused(const float* __restrict__ Whh0, const float* __restrict__ xg,
                const float* __restrict__ Wih1, const float* __restrict__ Whh1,
                const float* __restrict__ bih1, const float* __restrict__ bhh1,
                float* __restrict__ outF, Comm* __restrict__ cm)
{
    __shared__ float Wl[32 * HID];   // 131 KB: rows [w*4+gate][1024]
    __shared__ float hlA[HID];
    __shared__ float hlB[HID];
    __shared__ float hpubf[8];
    const int blk = blockIdx.x, tid = threadIdx.x;
    const int wave = tid >> 6, lane = tid & 63;

    if (blk < NBLK) {
        // ---------------- layer 0 ----------------
        const int k = blk;
        // stage W_hh0 slice: LDS row r=w*4+g <- global row g*1024 + (8k+w)
#pragma unroll
        for (int i = 0; i < 16; ++i) {
            int l = i * NTHR + tid;
            int r = l >> 8, c = l & 255;
            int w = r >> 2, g = r & 3;
            ((float4*)(Wl + r * HID))[c] =
                ((const float4*)(Whh0 + (size_t)(g * HID + 8 * k + w) * HID))[c];
        }
        for (int i = tid; i < HID; i += NTHR) hlA[i] = 0.f;
        float c_state = 0.f;
        // prefetch xg[0]
        float nx0 = 0.f, nx1 = 0.f, nx2 = 0.f, nx3 = 0.f;
        if (lane == 0) {
            const float* xp = xg + (size_t)0 * G4 + k * 32 + wave * 4;
            nx0 = xp[0]; nx1 = xp[1]; nx2 = xp[2]; nx3 = xp[3];
        }
        __syncthreads();

        for (int t = 0; t < T_STEPS; ++t) {
            const int p = t & 1;
            float x0 = nx0, x1 = nx1, x2 = nx2, x3 = nx3;
            if (lane == 0 && t + 1 < T_STEPS) {
                const float* xp = xg + (size_t)(t + 1) * G4 + k * 32 + wave * 4;
                nx0 = xp[0]; nx1 = xp[1]; nx2 = xp[2]; nx3 = xp[3];
            }
            float a0 = 0.f, a1 = 0.f, a2 = 0.f, a3 = 0.f;
            const float* wb = Wl + wave * 4 * HID;
#pragma unroll 4
            for (int u = 0; u < 16; ++u) {
                float hv = hlA[u * 64 + lane];
                a0 += wb[0 * HID + u * 64 + lane] * hv;
                a1 += wb[1 * HID + u * 64 + lane] * hv;
                a2 += wb[2 * HID + u * 64 + lane] * hv;
                a3 += wb[3 * HID + u * 64 + lane] * hv;
            }
#pragma unroll
            for (int off = 32; off > 0; off >>= 1) {
                a0 += __shfl_xor(a0, off, 64);
                a1 += __shfl_xor(a1, off, 64);
                a2 += __shfl_xor(a2, off, 64);
                a3 += __shfl_xor(a3, off, 64);
            }
            if (lane == 0) {
                float ig = sigm(x0 + a0);
                float fg = sigm(x1 + a1);
                float gg = tanh_f(x2 + a2);
                float og = sigm(x3 + a3);
                c_state = fg * c_state + ig * gg;
                hpubf[wave] = og * tanh_f(c_state);
            }
            __syncthreads();   // hpubf ready; all done reading hlA
            if (wave == 0) {
                if (lane < 4) {
                    union { float f[2]; ull u; } pk;
                    pk.f[0] = hpubf[2 * lane]; pk.f[1] = hpubf[2 * lane + 1];
                    __hip_atomic_store(&cm->hA[p][(size_t)k * 4 + lane], pk.u,
                                       __ATOMIC_RELAXED, __HIP_MEMORY_SCOPE_AGENT);
                }
                if (lane == 0)
                    __hip_atomic_store((int*)cm->flags + k, t + 1,
                                       __ATOMIC_RELEASE, __HIP_MEMORY_SCOPE_AGENT);
            }
            if (t == T_STEPS - 1) break;
            if (wave == 0) poll_flags(cm, t, lane);
            __syncthreads();
            {   // gather h0_t
                union { ull u; float f[2]; } cv;
                cv.u = __hip_atomic_load(&cm->hA[p][tid],
                                         __ATOMIC_RELAXED, __HIP_MEMORY_SCOPE_AGENT);
                hlA[2 * tid + 0] = cv.f[0];
                hlA[2 * tid + 1] = cv.f[1];
            }
            __syncthreads();
        }
    } else {
        // ---------------- layer 1 ----------------
        const int kk = blk - NBLK;
        const int j = 8 * kk + wave;   // owned h index
        // stage W_hh1 slice (LDS) + W_ih1 slice (registers)
#pragma unroll
        for (int i = 0; i < 16; ++i) {
            int l = i * NTHR + tid;
            int r = l >> 8, c = l & 255;
            int w = r >> 2, g = r & 3;
            ((float4*)(Wl + r * HID))[c] =
                ((const float4*)(Whh1 + (size_t)(g * HID + 8 * kk + w) * HID))[c];
        }
        float wreg[4][16];
#pragma unroll
        for (int g = 0; g < 4; ++g)
#pragma unroll
            for (int u = 0; u < 16; ++u)
                wreg[g][u] = Wih1[(size_t)(g * HID + j) * HID + u * 64 + lane];
        float bia[4];
#pragma unroll
        for (int g = 0; g < 4; ++g)
            bia[g] = bih1[g * HID + j] + bhh1[g * HID + j];
        float c_state = 0.f;
        __syncthreads();

        for (int t = 0; t < T_STEPS; ++t) {
            const int p = t & 1;
            if (wave == 0) poll_flags(cm, t, lane);
            __syncthreads();
            {   // gather h0_t (parity p) and h1_{t-1} (parity p^1)
                union { ull u; float f[2]; } cv;
                cv.u = __hip_atomic_load(&cm->hA[p][tid],
                                         __ATOMIC_RELAXED, __HIP_MEMORY_SCOPE_AGENT);
                hlA[2 * tid + 0] = cv.f[0];
                hlA[2 * tid + 1] = cv.f[1];
                cv.u = __hip_atomic_load(&cm->hB[p ^ 1][tid],
                                         __ATOMIC_RELAXED, __HIP_MEMORY_SCOPE_AGENT);
                hlB[2 * tid + 0] = cv.f[0];
                hlB[2 * tid + 1] = cv.f[1];
            }
            __syncthreads();
            float a0 = 0.f, a1 = 0.f, a2 = 0.f, a3 = 0.f;
            const float* wb = Wl + wave * 4 * HID;
#pragma unroll
            for (int u = 0; u < 16; ++u) {
                float h0v = hlA[u * 64 + lane];   // input from layer 0
                float h1v = hlB[u * 64 + lane];   // own recurrent state
                a0 += wb[0 * HID + u * 64 + lane] * h1v + wreg[0][u] * h0v;
                a1 += wb[1 * HID + u * 64 + lane] * h1v + wreg[1][u] * h0v;
                a2 += wb[2 * HID + u * 64 + lane] * h1v + wreg[2][u] * h0v;
                a3 += wb[3 * HID + u * 64 + lane] * h1v + wreg[3][u] * h0v;
            }
#pragma unroll
            for (int off = 32; off > 0; off >>= 1) {
                a0 += __shfl_xor(a0, off, 64);
                a1 += __shfl_xor(a1, off, 64);
                a2 += __shfl_xor(a2, off, 64);
                a3 += __shfl_xor(a3, off, 64);
            }
            float h = 0.f;
            if (lane == 0) {
                float ig = sigm(bia[0] + a0);
                float fg = sigm(bia[1] + a1);
                float gg = tanh_f(bia[2] + a2);
                float og = sigm(bia[3] + a3);
                c_state = fg * c_state + ig * gg;
                h = og * tanh_f(c_state);
            }
            if (t == T_STEPS - 1) {
                if (lane == 0) outF[j] = h;
                break;
            }
            if (lane == 0) hpubf[wave] = h;
            __syncthreads();   // hpubf ready; all done reading hlB
            if (wave == 0) {
                if (lane < 4) {
                    union { float f[2]; ull u; } pk;
                    pk.f[0] = hpubf[2 * lane]; pk.f[1] = hpubf[2 * lane + 1];
                    __hip_atomic_store(&cm->hB[p][(size_t)kk * 4 + lane], pk.u,
                                       __ATOMIC_RELAXED, __HIP_MEMORY_SCOPE_AGENT);
                }
                if (lane == 0)
                    __hip_atomic_store((int*)cm->flags + NBLK + kk, t + 1,
                                       __ATOMIC_RELEASE, __HIP_MEMORY_SCOPE_AGENT);
            }
        }
    }
}

extern "C" void kernel_launch(void* const* d_in, const int* in_sizes, int n_in,
                              void* d_out, int out_size, void* d_ws, size_t ws_size,
                              hipStream_t stream)
{
    const float* x    = (const float*)d_in[0];
    const float* Wih0 = (const float*)d_in[1];
    const float* Whh0 = (const float*)d_in[2];
    const float* bih0 = (const float*)d_in[3];
    const float* bhh0 = (const float*)d_in[4];
    const float* Wih1 = (const float*)d_in[5];
    const float* Whh1 = (const float*)d_in[6];
    const float* bih1 = (const float*)d_in[7];
    const float* bhh1 = (const float*)d_in[8];

    char* ws = (char*)d_ws;
    float* xg = (float*)ws;                     // 8192*4096*4 = 134217728 B
    Comm*  cm = (Comm*)(ws + 134217728);        // 17408 B

    (void)hipMemsetAsync(ws + 134217728, 0, sizeof(Comm), stream);

    dim3 gg(G4 / 64, T_STEPS / 64);
    gemm_xg<<<gg, 256, 0, stream>>>(x, Wih0, bih0, bhh0, xg);
    lstm_fused<<<2 * NBLK, NTHR, 0, stream>>>(Whh0, xg, Wih1, Whh1, bih1, bhh1,
                                              (float*)d_out, cm);
}

// Round 6
// 41642.163 us; speedup vs baseline: 10.6322x; 1.6277x over previous
//
#include <hip/hip_runtime.h>

#define T_STEPS 8192
#define HID 1024
#define G4 4096
#define NBLK 128    // blocks per layer; grid = 256
#define NTHR 512    // 8 waves

typedef unsigned long long ull;
typedef unsigned int uint32;

// Tagged-data comm (self-initialized to 0xFF each launch):
//   hA[s][1024], hB[s][1024] : fp32 h values with 4 LSBs of mantissa = tag.
//   Slot s = t & 3; tag = (t>>2) & 15. A word is valid for step t iff its
//   tag matches — each 32-bit load is an atomic snapshot, so no flags, no
//   release/acquire, no vmcnt drains anywhere on the critical path.
//   Overwrite safety (4-deep rotation): publishing h_t requires having
//   gathered h_{t-1}, which proves every same-cohort block is past step t-1,
//   hence done reading h_{t-4} (the slot being overwritten). Cross-cohort
//   (layer-1 reads hA): layer-0 wave1 spins on hB tags for t-3 during step
//   t's poll phase, proving all layer-1 blocks consumed h0_{t-3} before
//   layer-0 publishes h0_{t+1}.
struct Comm {
    uint32 hA[4][HID];
    uint32 hB[4][HID];
};

__device__ inline float sigm(float x) { return 1.0f / (1.0f + __expf(-x)); }
__device__ inline float tanh_f(float x) {
    x = fminf(fmaxf(x, -15.f), 15.f);
    float e = __expf(-2.0f * x);
    return (1.0f - e) / (1.0f + e);
}
__device__ inline uint32 tagf(float f, uint32 tg) {
    union { float f; uint32 u; } a; a.f = f;
    return (a.u & ~15u) | tg;
}

// out[m][perm(n)] = A[m][:] . W[n][:] + bi[n] + bh[n]
// perm: j = n&1023, gate = n>>10; idx = (j>>3)*32 + (j&7)*4 + gate
__global__ __launch_bounds__(256)
void gemm_xg(const float* __restrict__ A, const float* __restrict__ W,
             const float* __restrict__ bi, const float* __restrict__ bh,
             float* __restrict__ out)
{
    __shared__ float As[16][65];
    __shared__ float Bs[16][65];
    const int tid = threadIdx.x;
    const int m0 = blockIdx.y * 64, n0 = blockIdx.x * 64;
    const int tm = tid & 15, tn = tid >> 4;
    const int row = tid >> 2, q = tid & 3;
    float acc[4][4] = {{0.f}};
    for (int k0 = 0; k0 < HID; k0 += 16) {
        float4 a = *(const float4*)(A + (size_t)(m0 + row) * HID + k0 + q * 4);
        float4 b = *(const float4*)(W + (size_t)(n0 + row) * HID + k0 + q * 4);
        __syncthreads();
        As[q*4+0][row] = a.x; As[q*4+1][row] = a.y; As[q*4+2][row] = a.z; As[q*4+3][row] = a.w;
        Bs[q*4+0][row] = b.x; Bs[q*4+1][row] = b.y; Bs[q*4+2][row] = b.z; Bs[q*4+3][row] = b.w;
        __syncthreads();
#pragma unroll
        for (int kk = 0; kk < 16; ++kk) {
            float av[4], bv[4];
#pragma unroll
            for (int i = 0; i < 4; ++i) { av[i] = As[kk][tm*4+i]; bv[i] = Bs[kk][tn*4+i]; }
#pragma unroll
            for (int i = 0; i < 4; ++i)
#pragma unroll
                for (int j = 0; j < 4; ++j) acc[i][j] += av[i] * bv[j];
        }
    }
#pragma unroll
    for (int i = 0; i < 4; ++i) {
        int m = m0 + tm * 4 + i;
#pragma unroll
        for (int j = 0; j < 4; ++j) {
            int n = n0 + tn * 4 + j;
            float v = acc[i][j] + bi[n] + bh[n];
            int jd = n & (HID - 1), gate = n >> 10;
            out[(size_t)m * G4 + (jd >> 3) * 32 + (jd & 7) * 4 + gate] = v;
        }
    }
}

// Poll-and-gather: 16 tagged loads/lane (coalesced, pipelined); on full tag
// match the data is in registers -> ds_write. Returns nothing; fills lds[].
__device__ inline void poll_gather(const uint32* __restrict__ buf, uint32 tg,
                                   int lane, float* __restrict__ lds)
{
    uint32 v[16];
    for (;;) {
        bool ok = true;
#pragma unroll
        for (int r = 0; r < 16; ++r)
            v[r] = __hip_atomic_load(&buf[lane + 64 * r],
                                     __ATOMIC_RELAXED, __HIP_MEMORY_SCOPE_AGENT);
#pragma unroll
        for (int r = 0; r < 16; ++r) ok &= ((v[r] & 15u) == tg);
        if (__all(ok)) break;
    }
#pragma unroll
    for (int r = 0; r < 16; ++r) {
        union { uint32 u; float f; } c; c.u = v[r];
        lds[lane + 64 * r] = c.f;
    }
}

// Fused 2-layer persistent LSTM. 256 blocks x 512 thr, 1 block/CU.
// Blocks 0..127 = layer 0 (xg precomputed); blocks 128..255 = layer 1
// (W_ih1 slice in 64 VGPRs/thread, W_hh1 slice in LDS).
__global__ __launch_bounds__(NTHR)
void lstm_fused(const float* __restrict__ Whh0, const float* __restrict__ xg,
                const float* __restrict__ Wih1, const float* __restrict__ Whh1,
                const float* __restrict__ bih1, const float* __restrict__ bhh1,
                float* __restrict__ outF, Comm* __restrict__ cm)
{
    __shared__ float Wl[32 * HID];   // 131 KB
    __shared__ float hlA[HID];
    __shared__ float hlB[HID];
    const int blk = blockIdx.x, tid = threadIdx.x;
    const int wave = tid >> 6, lane = tid & 63;

    if (blk < NBLK) {
        // ---------------- layer 0 ----------------
        const int k = blk;
#pragma unroll
        for (int i = 0; i < 16; ++i) {
            int l = i * NTHR + tid;
            int r = l >> 8, c = l & 255;
            int w = r >> 2, g = r & 3;
            ((float4*)(Wl + r * HID))[c] =
                ((const float4*)(Whh0 + (size_t)(g * HID + 8 * k + w) * HID))[c];
        }
        for (int i = tid; i < HID; i += NTHR) hlA[i] = 0.f;
        float c_state = 0.f;
        float nx0 = 0.f, nx1 = 0.f, nx2 = 0.f, nx3 = 0.f;
        if (lane == 0) {
            const float* xp = xg + (size_t)0 * G4 + k * 32 + wave * 4;
            nx0 = xp[0]; nx1 = xp[1]; nx2 = xp[2]; nx3 = xp[3];
        }
        __syncthreads();

        for (int t = 0; t < T_STEPS; ++t) {
            float x0 = nx0, x1 = nx1, x2 = nx2, x3 = nx3;
            if (lane == 0 && t + 1 < T_STEPS) {
                const float* xp = xg + (size_t)(t + 1) * G4 + k * 32 + wave * 4;
                nx0 = xp[0]; nx1 = xp[1]; nx2 = xp[2]; nx3 = xp[3];
            }
            float a0 = 0.f, a1 = 0.f, a2 = 0.f, a3 = 0.f;
            const float* wb = Wl + wave * 4 * HID;
#pragma unroll 4
            for (int u = 0; u < 16; ++u) {
                float hv = hlA[u * 64 + lane];
                a0 += wb[0 * HID + u * 64 + lane] * hv;
                a1 += wb[1 * HID + u * 64 + lane] * hv;
                a2 += wb[2 * HID + u * 64 + lane] * hv;
                a3 += wb[3 * HID + u * 64 + lane] * hv;
            }
#pragma unroll
            for (int off = 32; off > 0; off >>= 1) {
                a0 += __shfl_xor(a0, off, 64);
                a1 += __shfl_xor(a1, off, 64);
                a2 += __shfl_xor(a2, off, 64);
                a3 += __shfl_xor(a3, off, 64);
            }
            if (lane == 0) {
                float ig = sigm(x0 + a0);
                float fg = sigm(x1 + a1);
                float gg = tanh_f(x2 + a2);
                float og = sigm(x3 + a3);
                c_state = fg * c_state + ig * gg;
                float h = og * tanh_f(c_state);
                // fire-and-forget tagged publish of h0_t
                __hip_atomic_store(&cm->hA[t & 3][8 * k + wave],
                                   tagf(h, (t >> 2) & 15),
                                   __ATOMIC_RELAXED, __HIP_MEMORY_SCOPE_AGENT);
            }
            if (t == T_STEPS - 1) break;
            __syncthreads();   // everyone done reading hlA
            if (wave == 0) {
                poll_gather(cm->hA[t & 3], (t >> 2) & 15, lane, hlA);
            } else if (wave == 1 && t >= 3) {
                // backpressure: h1_{t-3} published => layer-1 consumed h0_{t-3},
                // so next step's overwrite of slot (t+1)&3 is safe.
                const int s = t - 3;
                const uint32 tg = (s >> 2) & 15;
                const uint32* hb = cm->hB[s & 3];
                for (;;) {
                    uint32 b0 = __hip_atomic_load(&hb[8 * lane],
                                                  __ATOMIC_RELAXED, __HIP_MEMORY_SCOPE_AGENT);
                    uint32 b1 = __hip_atomic_load(&hb[8 * (lane + 64)],
                                                  __ATOMIC_RELAXED, __HIP_MEMORY_SCOPE_AGENT);
                    if (__all(((b0 & 15u) == tg) & ((b1 & 15u) == tg))) break;
                }
            }
            __syncthreads();   // hlA = h0_t
        }
    } else {
        // ---------------- layer 1 ----------------
        const int kk = blk - NBLK;
        const int j = 8 * kk + wave;
#pragma unroll
        for (int i = 0; i < 16; ++i) {
            int l = i * NTHR + tid;
            int r = l >> 8, c = l & 255;
            int w = r >> 2, g = r & 3;
            ((float4*)(Wl + r * HID))[c] =
                ((const float4*)(Whh1 + (size_t)(g * HID + 8 * kk + w) * HID))[c];
        }
        float wreg[4][16];
#pragma unroll
        for (int g = 0; g < 4; ++g)
#pragma unroll
            for (int u = 0; u < 16; ++u)
                wreg[g][u] = Wih1[(size_t)(g * HID + j) * HID + u * 64 + lane];
        float bia[4];
#pragma unroll
        for (int g = 0; g < 4; ++g)
            bia[g] = bih1[g * HID + j] + bhh1[g * HID + j];
        for (int i = tid; i < HID; i += NTHR) hlB[i] = 0.f;
        float c_state = 0.f;
        __syncthreads();

        for (int t = 0; t < T_STEPS; ++t) {
            if (wave == 0) {
                poll_gather(cm->hA[t & 3], (t >> 2) & 15, lane, hlA);      // h0_t
            } else if (wave == 1 && t >= 1) {
                const int s = t - 1;
                poll_gather(cm->hB[s & 3], (s >> 2) & 15, lane, hlB);      // h1_{t-1}
            }
            __syncthreads();
            float a0 = 0.f, a1 = 0.f, a2 = 0.f, a3 = 0.f;
            const float* wb = Wl + wave * 4 * HID;
#pragma unroll
            for (int u = 0; u < 16; ++u) {
                float h0v = hlA[u * 64 + lane];
                float h1v = hlB[u * 64 + lane];
                a0 += wb[0 * HID + u * 64 + lane] * h1v + wreg[0][u] * h0v;
                a1 += wb[1 * HID + u * 64 + lane] * h1v + wreg[1][u] * h0v;
                a2 += wb[2 * HID + u * 64 + lane] * h1v + wreg[2][u] * h0v;
                a3 += wb[3 * HID + u * 64 + lane] * h1v + wreg[3][u] * h0v;
            }
#pragma unroll
            for (int off = 32; off > 0; off >>= 1) {
                a0 += __shfl_xor(a0, off, 64);
                a1 += __shfl_xor(a1, off, 64);
                a2 += __shfl_xor(a2, off, 64);
                a3 += __shfl_xor(a3, off, 64);
            }
            if (lane == 0) {
                float ig = sigm(bia[0] + a0);
                float fg = sigm(bia[1] + a1);
                float gg = tanh_f(bia[2] + a2);
                float og = sigm(bia[3] + a3);
                c_state = fg * c_state + ig * gg;
                float h = og * tanh_f(c_state);
                if (t == T_STEPS - 1) {
                    outF[j] = h;   // untagged, full precision
                } else {
                    __hip_atomic_store(&cm->hB[t & 3][j],
                                       tagf(h, (t >> 2) & 15),
                                       __ATOMIC_RELAXED, __HIP_MEMORY_SCOPE_AGENT);
                }
            }
            if (t == T_STEPS - 1) break;
            __syncthreads();   // all done reading hlA/hlB before next gather
        }
    }
}

extern "C" void kernel_launch(void* const* d_in, const int* in_sizes, int n_in,
                              void* d_out, int out_size, void* d_ws, size_t ws_size,
                              hipStream_t stream)
{
    const float* x    = (const float*)d_in[0];
    const float* Wih0 = (const float*)d_in[1];
    const float* Whh0 = (const float*)d_in[2];
    const float* bih0 = (const float*)d_in[3];
    const float* bhh0 = (const float*)d_in[4];
    const float* Wih1 = (const float*)d_in[5];
    const float* Whh1 = (const float*)d_in[6];
    const float* bih1 = (const float*)d_in[7];
    const float* bhh1 = (const float*)d_in[8];

    char* ws = (char*)d_ws;
    float* xg = (float*)ws;                     // 8192*4096*4 = 134217728 B
    Comm*  cm = (Comm*)(ws + 134217728);        // 32768 B

    // 0xFF fill: tag bits = 15, mismatches tag 0 expected at t<4 (slots are
    // rewritten every 4 steps, so the init pattern is gone long before any
    // tag wraps back to 15).
    (void)hipMemsetAsync(ws + 134217728, 0xFF, sizeof(Comm), stream);

    dim3 gg(G4 / 64, T_STEPS / 64);
    gemm_xg<<<gg, 256, 0, stream>>>(x, Wih0, bih0, bhh0, xg);
    lstm_fused<<<2 * NBLK, NTHR, 0, stream>>>(Whh0, xg, Wih1, Whh1, bih1, bhh1,
                                              (float*)d_out, cm);
}